// Round 1
// baseline (352.450 us; speedup 1.0000x reference)
//
#include <hip/hip_runtime.h>

#define AS1 __attribute__((address_space(1)))
#define AS3 __attribute__((address_space(3)))

typedef __attribute__((ext_vector_type(8))) __bf16 bf16x8;
typedef __attribute__((ext_vector_type(4))) float f32x4;

static constexpr int Nn = 8192;   // rows of x
static constexpr int Mm = 8192;   // rows of x2
static constexpr int Dd = 512;    // feature dim
static constexpr float TINY = 1.17549435082228751e-38f;  // finfo(f32).tiny

__device__ __forceinline__ float softplus_f(float x) {
    // stable: max(x,0) + log1p(exp(-|x|)) == jax.nn.softplus
    return fmaxf(x, 0.0f) + log1pf(expf(-fabsf(x)));
}

__device__ __forceinline__ unsigned short f2bf(float f) {
    unsigned int u = __float_as_uint(f);
    u = (u + 0x7FFFu + ((u >> 16) & 1u)) >> 16;   // RNE
    return (unsigned short)u;
}

__device__ __forceinline__ void g2l16(const void* g, void* l) {
    // async global->LDS, 16B per lane; LDS dest = wave-uniform base + lane*16
    __builtin_amdgcn_global_load_lds((const AS1 unsigned int*)g,
                                     (AS3 unsigned int*)l, 16, 0, 0);
}

// ---------------------------------------------------------------------------
// Kernel 1: parameter transforms (1 block)
// ---------------------------------------------------------------------------
__global__ void prep_params(const float* __restrict__ amp_raw,
                            const float* __restrict__ ls_raw,
                            float* __restrict__ inv_l,
                            float* __restrict__ amp2) {
    int t = threadIdx.x;
    if (t < Dd) {
        float l = softplus_f(ls_raw[t]) + TINY;
        inv_l[t] = 1.0f / l;
    }
    if (t == 0) {
        float a = softplus_f(amp_raw[0]) + TINY;
        amp2[0] = a * a;
    }
}

// ---------------------------------------------------------------------------
// Kernel 2: scale rows to bf16 (XOR-swizzled 16B chunks) + fp32 row norms.
// One wave per row; lane i handles elements [i*8, i*8+8).
// Swizzle: logical chunk j stored at physical (j&~3)|((j&3)^g), g=(row>>1)&3.
// This makes the GEMM's ds_read_b128 pattern 2-way-conflict max (free, m136)
// while keeping global_load_lds's lane-linear LDS requirement intact.
// ---------------------------------------------------------------------------
__global__ __launch_bounds__(256) void scale_rows(
        const float* __restrict__ x, const float* __restrict__ x2,
        const float* __restrict__ inv_l,
        unsigned short* __restrict__ xs, unsigned short* __restrict__ ys,
        float* __restrict__ x_sq, float* __restrict__ y_sq) {
    int wave = threadIdx.x >> 6, lane = threadIdx.x & 63;
    int row = blockIdx.x * 4 + wave;            // 0 .. N+M-1

    const float* src; unsigned short* dst; float* nrm; int r;
    if (row < Nn) {
        src = x  + (size_t)row * Dd; dst = xs + (size_t)row * Dd;
        nrm = x_sq + row; r = row;
    } else {
        int m = row - Nn;
        src = x2 + (size_t)m * Dd;   dst = ys + (size_t)m * Dd;
        nrm = y_sq + m; r = m;
    }

    float4 v0 = ((const float4*)src)[lane * 2];
    float4 v1 = ((const float4*)src)[lane * 2 + 1];
    float4 l0 = ((const float4*)inv_l)[lane * 2];
    float4 l1 = ((const float4*)inv_l)[lane * 2 + 1];

    float s[8] = { v0.x*l0.x, v0.y*l0.y, v0.z*l0.z, v0.w*l0.w,
                   v1.x*l1.x, v1.y*l1.y, v1.z*l1.z, v1.w*l1.w };
    float sum = 0.0f;
    unsigned short h[8];
#pragma unroll
    for (int i = 0; i < 8; ++i) { sum += s[i] * s[i]; h[i] = f2bf(s[i]); }

    int g = (r >> 1) & 3;
    int chunk = (lane & ~3) | ((lane & 3) ^ g);
    int4 pk;
    pk.x = (int)h[0] | ((int)h[1] << 16);
    pk.y = (int)h[2] | ((int)h[3] << 16);
    pk.z = (int)h[4] | ((int)h[5] << 16);
    pk.w = (int)h[6] | ((int)h[7] << 16);
    *(int4*)(dst + (size_t)chunk * 8) = pk;

#pragma unroll
    for (int off = 32; off > 0; off >>= 1) sum += __shfl_down(sum, off, 64);
    if (lane == 0) *nrm = sum;
}

// ---------------------------------------------------------------------------
// Kernel 3: 128x128 bf16 MFMA GEMM with fused RBF epilogue.
// 256 threads = 4 waves (2x2), each wave does 4x4 tiles of 16x16x32.
// BK=32, K-iters = 16. global_load_lds(16B) staging, m97 2-barrier loop.
// ---------------------------------------------------------------------------
__global__ __launch_bounds__(256) void gemm_rbf(
        const unsigned short* __restrict__ xs,
        const unsigned short* __restrict__ ys,
        const float* __restrict__ x_sq, const float* __restrict__ y_sq,
        const float* __restrict__ amp2p, float* __restrict__ out) {

    __shared__ unsigned short sA[128 * 32];   // 8 KB
    __shared__ unsigned short sB[128 * 32];   // 8 KB

    const int tid  = threadIdx.x;
    const int wave = tid >> 6, lane = tid & 63;
    const int wy = wave >> 1, wx = wave & 1;
    const int lane15 = lane & 15, quad = lane >> 4;
    const int rA  = lane >> 2;      // staging: row within 16-row issue
    const int c16 = lane & 3;       // staging: 16B chunk within row

    const size_t rowBase = (size_t)blockIdx.y * 128;
    const size_t colBase = (size_t)blockIdx.x * 128;

    f32x4 acc[4][4] = {};
    const int gsw = (lane15 >> 1) & 3;   // g(r) for fragment rows

    for (int kt = 0; kt < 16; ++kt) {
        __syncthreads();
        const size_t kByte = (size_t)kt * 64;   // 32 bf16 per row per iter
#pragma unroll
        for (int t = 0; t < 2; ++t) {
            int issue = wave * 2 + t;          // 0..7 -> 16 LDS rows each
            int ldsRow = issue * 16 + rA;
            const char* ga = (const char*)(xs + (rowBase + ldsRow) * Dd)
                             + kByte + c16 * 16;
            g2l16(ga, sA + issue * 512);
            const char* gb = (const char*)(ys + (colBase + ldsRow) * Dd)
                             + kByte + c16 * 16;
            g2l16(gb, sB + issue * 512);
        }
        __syncthreads();

        bf16x8 aF[4], bF[4];
#pragma unroll
        for (int ty = 0; ty < 4; ++ty) {
            int rr = wy * 64 + ty * 16 + lane15;
            aF[ty] = *(const bf16x8*)(sA + rr * 32 + ((quad ^ gsw) * 8));
        }
#pragma unroll
        for (int tx = 0; tx < 4; ++tx) {
            int rr = wx * 64 + tx * 16 + lane15;
            bF[tx] = *(const bf16x8*)(sB + rr * 32 + ((quad ^ gsw) * 8));
        }
#pragma unroll
        for (int ty = 0; ty < 4; ++ty)
#pragma unroll
            for (int tx = 0; tx < 4; ++tx)
                acc[ty][tx] = __builtin_amdgcn_mfma_f32_16x16x32_bf16(
                    aF[ty], bF[tx], acc[ty][tx], 0, 0, 0);
    }

    // Epilogue: sq = max(x_sq + y_sq - 2*cross, 0); out = amp2*exp(-0.5*sq)
    // C/D layout: col = lane&15, row = quad*4 + reg (m89-verified)
    const float amp2 = *amp2p;
#pragma unroll
    for (int ty = 0; ty < 4; ++ty) {
        const size_t r0 = rowBase + wy * 64 + ty * 16 + quad * 4;
        float xq[4];
#pragma unroll
        for (int i = 0; i < 4; ++i) xq[i] = x_sq[r0 + i];
#pragma unroll
        for (int tx = 0; tx < 4; ++tx) {
            const size_t gc = colBase + wx * 64 + tx * 16 + lane15;
            const float yq = y_sq[gc];
            float* o = out + r0 * (size_t)Mm + gc;
#pragma unroll
            for (int reg = 0; reg < 4; ++reg) {
                float sq = fmaxf(xq[reg] + yq - 2.0f * acc[ty][tx][reg], 0.0f);
                o[(size_t)reg * Mm] = amp2 * __expf(-0.5f * sq);
            }
        }
    }
}

// ---------------------------------------------------------------------------
// Fallback (only if d_ws is too small): fused fp32 tile kernel, slow but exact.
// ---------------------------------------------------------------------------
__global__ __launch_bounds__(256) void rbf_fallback(
        const float* __restrict__ x, const float* __restrict__ x2,
        const float* __restrict__ amp_raw, const float* __restrict__ ls_raw,
        float* __restrict__ out) {
    __shared__ float il[Dd];
    __shared__ float sX[16 * Dd];
    __shared__ float sY[16 * Dd];
    int tid = threadIdx.x;
    for (int i = tid; i < Dd; i += 256)
        il[i] = 1.0f / (softplus_f(ls_raw[i]) + TINY);
    __syncthreads();
    int bR = blockIdx.y * 16, bC = blockIdx.x * 16;
    for (int i = tid; i < 16 * Dd; i += 256) {
        int r = i >> 9, c = i & (Dd - 1);
        sX[i] = x [(size_t)(bR + r) * Dd + c] * il[c];
        sY[i] = x2[(size_t)(bC + r) * Dd + c] * il[c];
    }
    __syncthreads();
    float a = softplus_f(amp_raw[0]) + TINY;
    float amp2 = a * a;
    int r = tid >> 4, c = tid & 15;
    float sq = 0.0f;
    for (int d = 0; d < Dd; ++d) {
        float df = sX[r * Dd + d] - sY[c * Dd + d];
        sq += df * df;
    }
    out[(size_t)(bR + r) * Mm + (bC + c)] = amp2 * __expf(-0.5f * sq);
}

extern "C" void kernel_launch(void* const* d_in, const int* in_sizes, int n_in,
                              void* d_out, int out_size, void* d_ws, size_t ws_size,
                              hipStream_t stream) {
    const float* x       = (const float*)d_in[0];
    const float* x2      = (const float*)d_in[1];
    const float* amp_raw = (const float*)d_in[2];
    const float* ls_raw  = (const float*)d_in[3];
    float* out = (float*)d_out;

    const size_t OFF_INVL = 0;                       // 512 f32
    const size_t OFF_AMP2 = 2048;                    // 1 f32
    const size_t OFF_XSQ  = 4096;                    // 8192 f32
    const size_t OFF_YSQ  = OFF_XSQ + 8192 * 4;      // 8192 f32
    const size_t OFF_XS   = OFF_YSQ + 8192 * 4;      // 8192*512 bf16
    const size_t OFF_YS   = OFF_XS + (size_t)Nn * Dd * 2;
    const size_t NEED     = OFF_YS + (size_t)Mm * Dd * 2;

    if (ws_size < NEED) {
        dim3 g(Mm / 16, Nn / 16);
        rbf_fallback<<<g, 256, 0, stream>>>(x, x2, amp_raw, ls_raw, out);
        return;
    }

    char* ws = (char*)d_ws;
    float* inv_l = (float*)(ws + OFF_INVL);
    float* amp2  = (float*)(ws + OFF_AMP2);
    float* x_sq  = (float*)(ws + OFF_XSQ);
    float* y_sq  = (float*)(ws + OFF_YSQ);
    unsigned short* xs = (unsigned short*)(ws + OFF_XS);
    unsigned short* ys = (unsigned short*)(ws + OFF_YS);

    prep_params<<<1, 512, 0, stream>>>(amp_raw, ls_raw, inv_l, amp2);
    scale_rows<<<(Nn + Mm) / 4, 256, 0, stream>>>(x, x2, inv_l, xs, ys, x_sq, y_sq);
    dim3 g(Mm / 128, Nn / 128);
    gemm_rbf<<<g, 256, 0, stream>>>(xs, ys, x_sq, y_sq, amp2, out);
}